// Round 8
// baseline (291.504 us; speedup 1.0000x reference)
//
#include <hip/hip_runtime.h>
#include <hip/hip_bf16.h>

// LowRankBilinearFusion on MI355X (gfx950) — v7
//
//  v6 -> v7: bilinear tile n32 x f256 (4096 blocks), acc[2][4] = 32 VGPR,
//  __launch_bounds__(256,6) -> 24 waves/CU (6 blocks x 17.4 KB LDS), 1.5x TLP,
//  halved per-block serial chain. Diagnosis: stall-bound (R3: all counters low;
//  v5->v6 occupancy 2->4 blocks bought ~8 us; VGPR was the binding constraint).
//
//  1. proj: unchanged (v3 structure): up_f32 = u@Wu^T; vp_bf = v@Wv^T; Wp->bf16.
//  2. bilinear: block = (b, n-quarter, m): o = relu( (vp (.) up) @ Wp^T + bp ).
//     Build A' (32x256 bf16, 16 KB, XOR-swz) once; barrier-free K-loop;
//     operand-swapped MFMA (f on regs) -> float4 stores.

typedef __attribute__((ext_vector_type(8))) short short8;
typedef __attribute__((ext_vector_type(4))) float floatx4;
typedef __attribute__((ext_vector_type(4))) unsigned uintx4;

__device__ __forceinline__ short f2bf(float f) {
    union { float f; unsigned u; } cv; cv.f = f;
    unsigned r = cv.u + 0x7fffu + ((cv.u >> 16) & 1u);
    return (short)(r >> 16);
}
// RNE pack of two fp32 into one dword of two bf16 (lo = x, hi = y).
__device__ __forceinline__ unsigned pack_rne(float x, float y) {
    __hip_bfloat162 h = __float22bfloat162_rn(make_float2(x, y));
    union { __hip_bfloat162 h; unsigned u; } cv; cv.h = h;
    return cv.u;
}
// (bf16 a)*ua, (bf16 b)*ub -> packed bf16 pair, RNE.
__device__ __forceinline__ unsigned scale2_rne(short a, short b, float ua, float ub) {
    float x = __uint_as_float(((unsigned)(unsigned short)a) << 16) * ua;
    float y = __uint_as_float(((unsigned)(unsigned short)b) << 16) * ub;
    return pack_rne(x, y);
}

#define MFMA16(a, b, c) __builtin_amdgcn_mfma_f32_16x16x32_bf16((a), (b), (c), 0, 0, 0)

// ---------------------------------------------------------------------------
// proj: 32x64 tiles. pidx 0..31 -> u (D=1024), 32..159 -> v (D=2048).
// 256 threads = 4 waves (2x2), wave tile 16x32. K-chunk 64. (v3 structure)
// Blocks 0..31 additionally convert Wp fp32 -> bf16 (8 elems/thread).
// ---------------------------------------------------------------------------
__global__ __launch_bounds__(256) void proj_kernel(
    const float* __restrict__ u, const float* __restrict__ Wu,
    float* __restrict__ upf,
    const float* __restrict__ v, const float* __restrict__ Wv,
    short* __restrict__ vpb,
    const float* __restrict__ Wp, short* __restrict__ Wp_bf)
{
    __shared__ __align__(16) short Xs[2][32 * 64];    // 4 KB each
    __shared__ __align__(16) short Wsh[2][64 * 64];   // 8 KB each

    const int tid  = threadIdx.x;
    const int lane = tid & 63;
    const int wave = tid >> 6;
    const int quad = lane >> 4;
    const int l15  = lane & 15;

    const int bid = blockIdx.x;

    // Wp fp32 -> bf16 (65536 elems over blocks 0..31)
    if (bid < 32) {
        const int widx = (bid * 256 + tid) * 8;
        float4 g0 = *(const float4*)(Wp + widx);
        float4 g1 = *(const float4*)(Wp + widx + 4);
        short8 o;
        o[0] = f2bf(g0.x); o[1] = f2bf(g0.y); o[2] = f2bf(g0.z); o[3] = f2bf(g0.w);
        o[4] = f2bf(g1.x); o[5] = f2bf(g1.y); o[6] = f2bf(g1.z); o[7] = f2bf(g1.w);
        *(short8*)(Wp_bf + widx) = o;
    }

    const int xcd = bid & 7, j = bid >> 3;
    const int cb  = j & 3;
    const int pidx = xcd + 8 * (j >> 2);              // 0..159
    const float *X, *W; int D, r0; bool is_u;
    if (pidx < 32) { is_u = true;  X = u; W = Wu; D = 1024; r0 = pidx * 32; }
    else           { is_u = false; X = v; W = Wv; D = 2048; r0 = (pidx - 32) * 32; }
    const int c0 = cb * 64;
    const int wr = (wave >> 1) * 16;                  // 0,16
    const int wc = (wave & 1) * 32;                   // 0,32

    const int xr_ = tid >> 3, xk = (tid & 7) * 8;
    const int wr_ = tid >> 2, wk = (tid & 3) * 16;
    const float* xg = X + (size_t)(r0 + xr_) * D + xk;
    const float* wg = W + (size_t)(c0 + wr_) * D + wk;
    const int xswz  = (xr_ & 7) << 4;
    const int wswz  = (wr_ & 7) << 4;
    const int xbase = xr_ * 128 + xk * 2;
    const int wbase = wr_ * 128 + wk * 2;

    floatx4 acc[2] = {};
    float4 x0, x1, y0, y1, y2, y3;

#define LDC(k)                                                                  \
    x0 = *(const float4*)(xg + (k));      x1 = *(const float4*)(xg + (k) + 4);  \
    y0 = *(const float4*)(wg + (k));      y1 = *(const float4*)(wg + (k) + 4);  \
    y2 = *(const float4*)(wg + (k) + 8);  y3 = *(const float4*)(wg + (k) + 12);

#define PKC(bi)                                                                 \
    { char* xb = (char*)&Xs[bi][0]; char* wb = (char*)&Wsh[bi][0]; uintx4 q;    \
      q[0] = pack_rne(x0.x, x0.y); q[1] = pack_rne(x0.z, x0.w);                 \
      q[2] = pack_rne(x1.x, x1.y); q[3] = pack_rne(x1.z, x1.w);                 \
      *(uintx4*)(xb + (xbase ^ xswz)) = q;                                      \
      q[0] = pack_rne(y0.x, y0.y); q[1] = pack_rne(y0.z, y0.w);                 \
      q[2] = pack_rne(y1.x, y1.y); q[3] = pack_rne(y1.z, y1.w);                 \
      *(uintx4*)(wb + (wbase ^ wswz)) = q;                                      \
      q[0] = pack_rne(y2.x, y2.y); q[1] = pack_rne(y2.z, y2.w);                 \
      q[2] = pack_rne(y3.x, y3.y); q[3] = pack_rne(y3.z, y3.w);                 \
      *(uintx4*)(wb + ((wbase + 16) ^ wswz)) = q; }

    LDC(0); PKC(0);
    __syncthreads();

    const int asw = (l15 & 7) << 4;
    int cur = 0;
    for (int kc = 0; kc < D; kc += 64) {
        const bool has = (kc + 64) < D;
        if (has) { LDC(kc + 64); }

        const char* xb = (const char*)&Xs[cur][0];
        const char* wb = (const char*)&Wsh[cur][0];
        short8 a0  = *(const short8*)(xb + (((wr + l15) * 128 +      quad * 16) ^ asw));
        short8 a1  = *(const short8*)(xb + (((wr + l15) * 128 + 64 + quad * 16) ^ asw));
        short8 b00 = *(const short8*)(wb + (((wc +      l15) * 128 +      quad * 16) ^ asw));
        short8 b01 = *(const short8*)(wb + (((wc +      l15) * 128 + 64 + quad * 16) ^ asw));
        short8 b10 = *(const short8*)(wb + (((wc + 16 + l15) * 128 +      quad * 16) ^ asw));
        short8 b11 = *(const short8*)(wb + (((wc + 16 + l15) * 128 + 64 + quad * 16) ^ asw));
        acc[0] = MFMA16(a0, b00, acc[0]);
        acc[1] = MFMA16(a0, b10, acc[1]);
        acc[0] = MFMA16(a1, b01, acc[0]);
        acc[1] = MFMA16(a1, b11, acc[1]);

        if (has) { PKC(cur ^ 1); }
        __syncthreads();
        cur ^= 1;
    }
#undef LDC
#undef PKC

    if (is_u) {
#pragma unroll
        for (int tf = 0; tf < 2; tf++)
#pragma unroll
            for (int r = 0; r < 4; r++) {
                const int row = r0 + wr + quad * 4 + r;
                const int col = c0 + wc + tf * 16 + l15;
                upf[(size_t)row * 256 + col] = acc[tf][r];
            }
    } else {
#pragma unroll
        for (int tf = 0; tf < 2; tf++)
#pragma unroll
            for (int r = 0; r < 4; r++) {
                const int row = r0 + wr + quad * 4 + r;
                const int col = c0 + wc + tf * 16 + l15;
                vpb[(size_t)row * 256 + col] = f2bf(acc[tf][r]);
            }
    }
}

// ---------------------------------------------------------------------------
// bilinear v7: block = (b, n-quarter, m); n32 x f256; 16 KB A' LDS;
// 6 blocks/CU (launch_bounds(256,6)). Build streams one chunk at a time
// (low reg pressure); barrier-free K-loop; acc[2][4].
// ---------------------------------------------------------------------------
__global__ __launch_bounds__(256, 6) void bilinear_kernel(
    const float* __restrict__ up, const short* __restrict__ vp,
    const short* __restrict__ Wp_bf, const float* __restrict__ bp,
    float* __restrict__ out)
{
    __shared__ __align__(16) short A_lds[32 * 256];   // 16 KB, swizzled
    __shared__ float up_s[256];

    const int tid  = threadIdx.x;
    const int lane = tid & 63;
    const int wave = tid >> 6;
    const int quad = lane >> 4;
    const int l15  = lane & 15;

    // XCD-aware decode: 4096 blocks = 8 xcd x 512. The 128 blocks of one b
    // (32 m x 4 nq) share bid%8 == b%8.
    const int bid = blockIdx.x;
    const int xcd = bid & 7;
    const int grp = bid >> 3;                 // 0..511
    const int s   = grp & 127;                // 0..127 within b-group
    const int b   = (grp >> 7) * 8 + xcd;     // 0..31
    const int m   = s >> 2;
    const int nq  = s & 3;
    const int bm  = b * 32 + m;
    const int n0  = nq * 32;

    // stage up row (1 float/thread; L2/L3-hot)
    up_s[tid] = up[(size_t)bm * 256 + tid];
    __syncthreads();                          // up_s ready

    // build A' = vp (.) up: 32 rows x 256 k. thread -> (row, 32-k segment),
    // streamed one short8 chunk at a time (12 live VGPRs).
    {
        const int row  = tid >> 3;            // 0..31
        const int kseg = (tid & 7) * 32;      // 0..224
        const short* vsrc = vp + (size_t)(b * 128 + n0 + row) * 256 + kseg;
        char* Ab = (char*)A_lds;
        const int rsw   = (row & 7) << 4;
        const int rbase = row * 512 + kseg * 2;
#pragma unroll
        for (int i = 0; i < 4; i++) {
            short8 vv = *(const short8*)(vsrc + i * 8);
            const float4 ua = *(const float4*)&up_s[kseg + i * 8];
            const float4 ub = *(const float4*)&up_s[kseg + i * 8 + 4];
            uintx4 o;
            o[0] = scale2_rne(vv[0], vv[1], ua.x, ua.y);
            o[1] = scale2_rne(vv[2], vv[3], ua.z, ua.w);
            o[2] = scale2_rne(vv[4], vv[5], ub.x, ub.y);
            o[3] = scale2_rne(vv[6], vv[7], ub.z, ub.w);
            *(uintx4*)(Ab + ((rbase + i * 16) ^ rsw)) = o;
        }
    }
    __syncthreads();                          // A' ready; NO MORE BARRIERS

    // barrier-free K-loop (operand-swapped: D-rows = f, D-cols = n)
    floatx4 acc[2][4] = {};
    const char* Ab = (const char*)A_lds;
    const int aswz = (l15 & 7) << 4;
    const int wf   = wave * 64;               // wave-uniform f-quarter
    const short* wq = Wp_bf + (size_t)(wf + l15) * 256 + quad * 8;

    short8 bcur[4], bnxt[4];
#pragma unroll
    for (int tt = 0; tt < 4; tt++)
        bcur[tt] = *(const short8*)(wq + tt * 4096);

#pragma unroll
    for (int kc = 0; kc < 256; kc += 32) {
        if (kc < 224) {   // prefetch next chunk's B-frags (L2-hot Wp)
#pragma unroll
            for (int tt = 0; tt < 4; tt++)
                bnxt[tt] = *(const short8*)(wq + tt * 4096 + kc + 32);
        }
        short8 a[2];
#pragma unroll
        for (int tt = 0; tt < 2; tt++) {
            const int row = tt * 16 + l15;    // n-rows 0..31
            a[tt] = *(const short8*)(Ab + ((row * 512 + kc * 2 + quad * 16) ^ aswz));
        }
        __builtin_amdgcn_s_setprio(1);
#pragma unroll
        for (int tn = 0; tn < 2; tn++)
#pragma unroll
            for (int tf = 0; tf < 4; tf++)
                acc[tn][tf] = MFMA16(bcur[tf], a[tn], acc[tn][tf]);
        __builtin_amdgcn_s_setprio(0);
        if (kc < 224) {
#pragma unroll
            for (int tt = 0; tt < 4; tt++) bcur[tt] = bnxt[tt];
        }
    }

    // epilogue: f = wf + tf*16 + quad*4 + r (consecutive in r); n = n0+tn*16+l15
    float4 bpv[4];
#pragma unroll
    for (int tf = 0; tf < 4; tf++)
        bpv[tf] = *(const float4*)&bp[wf + tf * 16 + quad * 4];

    const size_t out_base = (size_t)bm * 128 * 256 + (size_t)n0 * 256;
#pragma unroll
    for (int tn = 0; tn < 2; tn++) {
        const int n = tn * 16 + l15;
        float* orow = out + out_base + (size_t)n * 256 + wf + quad * 4;
#pragma unroll
        for (int tf = 0; tf < 4; tf++) {
            float4 vo;
            vo.x = fmaxf(acc[tn][tf][0] + bpv[tf].x, 0.0f);
            vo.y = fmaxf(acc[tn][tf][1] + bpv[tf].y, 0.0f);
            vo.z = fmaxf(acc[tn][tf][2] + bpv[tf].z, 0.0f);
            vo.w = fmaxf(acc[tn][tf][3] + bpv[tf].w, 0.0f);
            *(float4*)(orow + tf * 16) = vo;
        }
    }
}

extern "C" void kernel_launch(void* const* d_in, const int* in_sizes, int n_in,
                              void* d_out, int out_size, void* d_ws, size_t ws_size,
                              hipStream_t stream) {
    const float* u  = (const float*)d_in[0];   // (32,32,1024)
    const float* v  = (const float*)d_in[1];   // (32,128,2048)
    const float* Wu = (const float*)d_in[2];   // (256,1024)
    const float* Wv = (const float*)d_in[3];   // (256,2048)
    const float* Wp = (const float*)d_in[4];   // (256,256)
    const float* bp = (const float*)d_in[5];   // (256,)
    float* out = (float*)d_out;                // (32,32,128,256)

    float* up_f  = (float*)d_ws;               // 1024*256 fp32
    short* vp_bf = (short*)(up_f + 262144);    // 4096*256 bf16
    short* Wp_bf = vp_bf + 1048576;            // 256*256 bf16

    proj_kernel<<<dim3(640), dim3(256), 0, stream>>>(
        u, Wu, up_f, v, Wv, vp_bf, Wp, Wp_bf);
    bilinear_kernel<<<dim3(4096), dim3(256), 0, stream>>>(
        up_f, vp_bf, Wp_bf, bp, out);
}

// Round 9
// 258.566 us; speedup vs baseline: 1.1274x; 1.1274x over previous
//
#include <hip/hip_runtime.h>
#include <hip/hip_bf16.h>

// LowRankBilinearFusion on MI355X (gfx950) — v8
//
//  R8 diagnosis: v7's launch_bounds(256,6) spilled (VGPR=40 vs ~80 live;
//  FETCH 3.9->35MB, WRITE 131->206MB = scratch traffic; MfmaUtil fell to 5.4).
//  Also A_lds 512B-row swizzle conflicts (4.2M cycles). Deeper: each A' element
//  is written once / read once per block -> the LDS round-trip is pure overhead.
//
//  v8 bilinear: ZERO LDS, ZERO barriers. Each wave independently computes
//  (b, n64-half, m, f64-quarter): MFMA B-fragment built in registers as
//  bf16(vp_frag * up_frag) from L2-hot vp (64KB/b) + L1-broadcast up;
//  A-operand = Wp_bf fragments from L2-hot 128KB. acc[4][4]=64 VGPR,
//  lb(256,4) -> 16 waves/CU. #pragma unroll 2 caps load-hoisting (no spill).
//
//  1. proj: unchanged (v3 structure): up_f32 = u@Wu^T; vp_bf = v@Wv^T; Wp->bf16.

typedef __attribute__((ext_vector_type(8))) short short8;
typedef __attribute__((ext_vector_type(4))) float floatx4;
typedef __attribute__((ext_vector_type(4))) unsigned uintx4;

__device__ __forceinline__ short f2bf(float f) {
    union { float f; unsigned u; } cv; cv.f = f;
    unsigned r = cv.u + 0x7fffu + ((cv.u >> 16) & 1u);
    return (short)(r >> 16);
}
// RNE pack of two fp32 into one dword of two bf16 (lo = x, hi = y).
__device__ __forceinline__ unsigned pack_rne(float x, float y) {
    __hip_bfloat162 h = __float22bfloat162_rn(make_float2(x, y));
    union { __hip_bfloat162 h; unsigned u; } cv; cv.h = h;
    return cv.u;
}
// (bf16 a)*ua, (bf16 b)*ub -> packed bf16 pair, RNE.
__device__ __forceinline__ unsigned scale2_rne(short a, short b, float ua, float ub) {
    float x = __uint_as_float(((unsigned)(unsigned short)a) << 16) * ua;
    float y = __uint_as_float(((unsigned)(unsigned short)b) << 16) * ub;
    return pack_rne(x, y);
}

#define MFMA16(a, b, c) __builtin_amdgcn_mfma_f32_16x16x32_bf16((a), (b), (c), 0, 0, 0)

// ---------------------------------------------------------------------------
// proj: 32x64 tiles. pidx 0..31 -> u (D=1024), 32..159 -> v (D=2048).
// 256 threads = 4 waves (2x2), wave tile 16x32. K-chunk 64. (v3 structure)
// Blocks 0..31 additionally convert Wp fp32 -> bf16 (8 elems/thread).
// ---------------------------------------------------------------------------
__global__ __launch_bounds__(256) void proj_kernel(
    const float* __restrict__ u, const float* __restrict__ Wu,
    float* __restrict__ upf,
    const float* __restrict__ v, const float* __restrict__ Wv,
    short* __restrict__ vpb,
    const float* __restrict__ Wp, short* __restrict__ Wp_bf)
{
    __shared__ __align__(16) short Xs[2][32 * 64];    // 4 KB each
    __shared__ __align__(16) short Wsh[2][64 * 64];   // 8 KB each

    const int tid  = threadIdx.x;
    const int lane = tid & 63;
    const int wave = tid >> 6;
    const int quad = lane >> 4;
    const int l15  = lane & 15;

    const int bid = blockIdx.x;

    // Wp fp32 -> bf16 (65536 elems over blocks 0..31)
    if (bid < 32) {
        const int widx = (bid * 256 + tid) * 8;
        float4 g0 = *(const float4*)(Wp + widx);
        float4 g1 = *(const float4*)(Wp + widx + 4);
        short8 o;
        o[0] = f2bf(g0.x); o[1] = f2bf(g0.y); o[2] = f2bf(g0.z); o[3] = f2bf(g0.w);
        o[4] = f2bf(g1.x); o[5] = f2bf(g1.y); o[6] = f2bf(g1.z); o[7] = f2bf(g1.w);
        *(short8*)(Wp_bf + widx) = o;
    }

    const int xcd = bid & 7, j = bid >> 3;
    const int cb  = j & 3;
    const int pidx = xcd + 8 * (j >> 2);              // 0..159
    const float *X, *W; int D, r0; bool is_u;
    if (pidx < 32) { is_u = true;  X = u; W = Wu; D = 1024; r0 = pidx * 32; }
    else           { is_u = false; X = v; W = Wv; D = 2048; r0 = (pidx - 32) * 32; }
    const int c0 = cb * 64;
    const int wr = (wave >> 1) * 16;                  // 0,16
    const int wc = (wave & 1) * 32;                   // 0,32

    const int xr_ = tid >> 3, xk = (tid & 7) * 8;
    const int wr_ = tid >> 2, wk = (tid & 3) * 16;
    const float* xg = X + (size_t)(r0 + xr_) * D + xk;
    const float* wg = W + (size_t)(c0 + wr_) * D + wk;
    const int xswz  = (xr_ & 7) << 4;
    const int wswz  = (wr_ & 7) << 4;
    const int xbase = xr_ * 128 + xk * 2;
    const int wbase = wr_ * 128 + wk * 2;

    floatx4 acc[2] = {};
    float4 x0, x1, y0, y1, y2, y3;

#define LDC(k)                                                                  \
    x0 = *(const float4*)(xg + (k));      x1 = *(const float4*)(xg + (k) + 4);  \
    y0 = *(const float4*)(wg + (k));      y1 = *(const float4*)(wg + (k) + 4);  \
    y2 = *(const float4*)(wg + (k) + 8);  y3 = *(const float4*)(wg + (k) + 12);

#define PKC(bi)                                                                 \
    { char* xb = (char*)&Xs[bi][0]; char* wb = (char*)&Wsh[bi][0]; uintx4 q;    \
      q[0] = pack_rne(x0.x, x0.y); q[1] = pack_rne(x0.z, x0.w);                 \
      q[2] = pack_rne(x1.x, x1.y); q[3] = pack_rne(x1.z, x1.w);                 \
      *(uintx4*)(xb + (xbase ^ xswz)) = q;                                      \
      q[0] = pack_rne(y0.x, y0.y); q[1] = pack_rne(y0.z, y0.w);                 \
      q[2] = pack_rne(y1.x, y1.y); q[3] = pack_rne(y1.z, y1.w);                 \
      *(uintx4*)(wb + (wbase ^ wswz)) = q;                                      \
      q[0] = pack_rne(y2.x, y2.y); q[1] = pack_rne(y2.z, y2.w);                 \
      q[2] = pack_rne(y3.x, y3.y); q[3] = pack_rne(y3.z, y3.w);                 \
      *(uintx4*)(wb + ((wbase + 16) ^ wswz)) = q; }

    LDC(0); PKC(0);
    __syncthreads();

    const int asw = (l15 & 7) << 4;
    int cur = 0;
    for (int kc = 0; kc < D; kc += 64) {
        const bool has = (kc + 64) < D;
        if (has) { LDC(kc + 64); }

        const char* xb = (const char*)&Xs[cur][0];
        const char* wb = (const char*)&Wsh[cur][0];
        short8 a0  = *(const short8*)(xb + (((wr + l15) * 128 +      quad * 16) ^ asw));
        short8 a1  = *(const short8*)(xb + (((wr + l15) * 128 + 64 + quad * 16) ^ asw));
        short8 b00 = *(const short8*)(wb + (((wc +      l15) * 128 +      quad * 16) ^ asw));
        short8 b01 = *(const short8*)(wb + (((wc +      l15) * 128 + 64 + quad * 16) ^ asw));
        short8 b10 = *(const short8*)(wb + (((wc + 16 + l15) * 128 +      quad * 16) ^ asw));
        short8 b11 = *(const short8*)(wb + (((wc + 16 + l15) * 128 + 64 + quad * 16) ^ asw));
        acc[0] = MFMA16(a0, b00, acc[0]);
        acc[1] = MFMA16(a0, b10, acc[1]);
        acc[0] = MFMA16(a1, b01, acc[0]);
        acc[1] = MFMA16(a1, b11, acc[1]);

        if (has) { PKC(cur ^ 1); }
        __syncthreads();
        cur ^= 1;
    }
#undef LDC
#undef PKC

    if (is_u) {
#pragma unroll
        for (int tf = 0; tf < 2; tf++)
#pragma unroll
            for (int r = 0; r < 4; r++) {
                const int row = r0 + wr + quad * 4 + r;
                const int col = c0 + wc + tf * 16 + l15;
                upf[(size_t)row * 256 + col] = acc[tf][r];
            }
    } else {
#pragma unroll
        for (int tf = 0; tf < 2; tf++)
#pragma unroll
            for (int r = 0; r < 4; r++) {
                const int row = r0 + wr + quad * 4 + r;
                const int col = c0 + wc + tf * 16 + l15;
                vpb[(size_t)row * 256 + col] = f2bf(acc[tf][r]);
            }
    }
}

// ---------------------------------------------------------------------------
// bilinear v8: LDS-free, barrier-free. Block = (b, n-half, m); wave = f64.
// B-frag (A'=vp(.)up) built in registers; A-frag = Wp_bf; both L2-hot.
// ---------------------------------------------------------------------------
__global__ __launch_bounds__(256, 4) void bilinear_kernel(
    const float* __restrict__ up, const short* __restrict__ vp,
    const short* __restrict__ Wp_bf, const float* __restrict__ bp,
    float* __restrict__ out)
{
    const int tid  = threadIdx.x;
    const int lane = tid & 63;
    const int wave = tid >> 6;
    const int quad = lane >> 4;
    const int l15  = lane & 15;

    // XCD-aware decode: the 64 blocks of one b (32 m x 2 nhalf) share bid%8.
    const int bid = blockIdx.x;
    const int xcd = bid & 7;
    const int grp = bid >> 3;                 // 0..255
    const int s   = grp & 63;
    const int b   = (grp >> 6) * 8 + xcd;     // 0..31
    const int m   = s >> 1;
    const int nh  = s & 1;
    const int bm  = b * 32 + m;
    const int n0  = nh * 64;
    const int wf  = wave * 64;                // wave-uniform f-quarter

    // per-lane base pointers (all reads L1/L2-hot)
    const short* vrow = vp + (size_t)(b * 128 + n0 + l15) * 256 + quad * 8;
    const float* urow = up + (size_t)bm * 256 + quad * 8;       // quad-uniform
    const short* wrow = Wp_bf + (size_t)(wf + l15) * 256 + quad * 8;

    floatx4 acc[4][4] = {};

#pragma unroll 2
    for (int kc = 0; kc < 256; kc += 32) {
        // up slice (32B, uniform across the 16 lanes of a quad -> broadcast)
        const float4 u0 = *(const float4*)(urow + kc);
        const float4 u1 = *(const float4*)(urow + kc + 4);
        // Wp fragments (A-operand): rows wf+tt*16+l15
        short8 bb[4];
#pragma unroll
        for (int tt = 0; tt < 4; tt++)
            bb[tt] = *(const short8*)(wrow + tt * 4096 + kc);
        // vp fragments -> B-operand a[tt] = bf16(vp * up)
        short8 a[4];
#pragma unroll
        for (int tt = 0; tt < 4; tt++) {
            short8 vv = *(const short8*)(vrow + tt * 4096 + kc);
            uintx4 o;
            o[0] = scale2_rne(vv[0], vv[1], u0.x, u0.y);
            o[1] = scale2_rne(vv[2], vv[3], u0.z, u0.w);
            o[2] = scale2_rne(vv[4], vv[5], u1.x, u1.y);
            o[3] = scale2_rne(vv[6], vv[7], u1.z, u1.w);
            union { uintx4 u; short8 s; } cv; cv.u = o;
            a[tt] = cv.s;
        }
        __builtin_amdgcn_s_setprio(1);
#pragma unroll
        for (int tn = 0; tn < 4; tn++)
#pragma unroll
            for (int tf = 0; tf < 4; tf++)
                acc[tn][tf] = MFMA16(bb[tf], a[tn], acc[tn][tf]);
        __builtin_amdgcn_s_setprio(0);
    }

    // epilogue: f = wf + tf*16 + quad*4 + r (consecutive in r); n = n0+tn*16+l15
    float4 bpv[4];
#pragma unroll
    for (int tf = 0; tf < 4; tf++)
        bpv[tf] = *(const float4*)&bp[wf + tf * 16 + quad * 4];

    const size_t out_base = (size_t)bm * 128 * 256 + (size_t)n0 * 256;
#pragma unroll
    for (int tn = 0; tn < 4; tn++) {
        const int n = tn * 16 + l15;
        float* orow = out + out_base + (size_t)n * 256 + wf + quad * 4;
#pragma unroll
        for (int tf = 0; tf < 4; tf++) {
            float4 vo;
            vo.x = fmaxf(acc[tn][tf][0] + bpv[tf].x, 0.0f);
            vo.y = fmaxf(acc[tn][tf][1] + bpv[tf].y, 0.0f);
            vo.z = fmaxf(acc[tn][tf][2] + bpv[tf].z, 0.0f);
            vo.w = fmaxf(acc[tn][tf][3] + bpv[tf].w, 0.0f);
            *(float4*)(orow + tf * 16) = vo;
        }
    }
}

extern "C" void kernel_launch(void* const* d_in, const int* in_sizes, int n_in,
                              void* d_out, int out_size, void* d_ws, size_t ws_size,
                              hipStream_t stream) {
    const float* u  = (const float*)d_in[0];   // (32,32,1024)
    const float* v  = (const float*)d_in[1];   // (32,128,2048)
    const float* Wu = (const float*)d_in[2];   // (256,1024)
    const float* Wv = (const float*)d_in[3];   // (256,2048)
    const float* Wp = (const float*)d_in[4];   // (256,256)
    const float* bp = (const float*)d_in[5];   // (256,)
    float* out = (float*)d_out;                // (32,32,128,256)

    float* up_f  = (float*)d_ws;               // 1024*256 fp32
    short* vp_bf = (short*)(up_f + 262144);    // 4096*256 bf16
    short* Wp_bf = vp_bf + 1048576;            // 256*256 bf16

    proj_kernel<<<dim3(640), dim3(256), 0, stream>>>(
        u, Wu, up_f, v, Wv, vp_bf, Wp, Wp_bf);
    bilinear_kernel<<<dim3(2048), dim3(256), 0, stream>>>(
        up_f, vp_bf, Wp_bf, bp, out);
}

// Round 11
// 235.492 us; speedup vs baseline: 1.2379x; 1.0980x over previous
//
#include <hip/hip_runtime.h>
#include <hip/hip_bf16.h>

// LowRankBilinearFusion on MI355X (gfx950) — v9 (resubmit; R10 was an infra flake)
//
//  R9 accounting: per-iter fill floor is ~97.5 us (537MB ws + 134MB out poison),
//  NOT 156 -> proj has been ~70 us since v3 (consistent across R3/R8/R9).
//  proj got slow in v2 when convert was fused (fp32 reg-staging, 2x bytes,
//  no GL2LDS). v9 reverts: convert pass + pure-bf16 GL2LDS proj + v6 bilinear.
//
//  1. convert: u,v,Wu,Wv,Wp fp32 -> bf16 (RNE), ~10 us.
//  2. proj: bf16 GEMM. up_f32 = u@Wu^T; vp_bf = v@Wv^T. 64x128 tiles,
//     160 blocks (128 v + 32 u), K-chunk 32, dbuf GL2LDS (stage t+1 during t),
//     source-slot-XOR staging (v3's verified conflict-free pattern).
//     XCD grouping: same-XCD blocks share full W (1MB bf16, L2-resident).
//  3. bilinear: v6 verbatim (best measured ~63 us): block=(b,nhalf,m), n64xf256,
//     A'=vp(.)up built once in 32KB LDS, barrier-free K-loop, B=Wp_bf from L2.

typedef __attribute__((ext_vector_type(8))) short short8;
typedef __attribute__((ext_vector_type(4))) float floatx4;
typedef __attribute__((ext_vector_type(4))) unsigned uintx4;

__device__ __forceinline__ short f2bf(float f) {
    union { float f; unsigned u; } cv; cv.f = f;
    unsigned r = cv.u + 0x7fffu + ((cv.u >> 16) & 1u);
    return (short)(r >> 16);
}
__device__ __forceinline__ unsigned pack_rne(float x, float y) {
    __hip_bfloat162 h = __float22bfloat162_rn(make_float2(x, y));
    union { __hip_bfloat162 h; unsigned u; } cv; cv.h = h;
    return cv.u;
}
// (bf16 a)*ua, (bf16 b)*ub -> packed bf16 pair, RNE.
__device__ __forceinline__ unsigned scale2_rne(short a, short b, float ua, float ub) {
    float x = __uint_as_float(((unsigned)(unsigned short)a) << 16) * ua;
    float y = __uint_as_float(((unsigned)(unsigned short)b) << 16) * ub;
    return pack_rne(x, y);
}

#define GL2LDS(gptr, lptr) __builtin_amdgcn_global_load_lds(                    \
    (const __attribute__((address_space(1))) void*)(gptr),                      \
    (__attribute__((address_space(3))) void*)(lptr), 16, 0, 0)

#define MFMA16(a, b, c) __builtin_amdgcn_mfma_f32_16x16x32_bf16((a), (b), (c), 0, 0, 0)

// ---------------------------------------------------------------------------
#define N_U  1048576
#define N_V  8388608
#define N_WU 262144
#define N_WV 524288
#define N_WP 65536

__global__ __launch_bounds__(256) void convert_kernel(
    const float* __restrict__ u, const float* __restrict__ v,
    const float* __restrict__ Wu, const float* __restrict__ Wv,
    const float* __restrict__ Wp, short* __restrict__ dst)
{
    const int n_u = N_U / 4, n_v = N_V / 4, n_wu = N_WU / 4, n_wv = N_WV / 4,
              n_wp = N_WP / 4;
    const int total = n_u + n_v + n_wu + n_wv + n_wp;
    for (int i4 = blockIdx.x * blockDim.x + threadIdx.x; i4 < total;
         i4 += gridDim.x * blockDim.x) {
        const float* src; int off = i4;
        if (off < n_u) src = u;
        else { off -= n_u;
            if (off < n_v) src = v;
            else { off -= n_v;
                if (off < n_wu) src = Wu;
                else { off -= n_wu;
                    if (off < n_wv) src = Wv;
                    else { off -= n_wv; src = Wp; } } } }
        float4 f = *((const float4*)src + off);
        short4 o;
        o.x = f2bf(f.x); o.y = f2bf(f.y); o.z = f2bf(f.z); o.w = f2bf(f.w);
        *((short4*)dst + i4) = o;
    }
}

// ---------------------------------------------------------------------------
// proj: bf16 GEMM via GL2LDS, dbuf, K-chunk 32. Block tile 64(M) x 128(N).
// bid 0..127: v-proj (D=2048, 64 rpanels x 2 cpanels);
// bid 128..159: u-proj (D=1024, 16 rpanels x 2 cpanels).
// Same-XCD blocks share the full W in L2. 4 waves (2x2) of 32x64.
// ---------------------------------------------------------------------------
__global__ __launch_bounds__(256) void proj_kernel(
    const short* __restrict__ Xu, const short* __restrict__ Wgu,
    float* __restrict__ upf,
    const short* __restrict__ Xv, const short* __restrict__ Wgv,
    short* __restrict__ vpb)
{
    __shared__ __align__(16) short Xs[2][64 * 32];    // 4 KB each
    __shared__ __align__(16) short Wsh[2][128 * 32];  // 8 KB each

    const int tid  = threadIdx.x;
    const int lane = tid & 63;
    const int wave = tid >> 6;
    const int quad = lane >> 4;
    const int l15  = lane & 15;

    const int bid = blockIdx.x;
    const short *X, *W; int D; bool is_u; int xcd, t;
    if (bid < 128) {
        is_u = false; X = Xv; W = Wgv; D = 2048;
        xcd = bid & 7; t = bid >> 3;              // t 0..15
    } else {
        is_u = true;  X = Xu; W = Wgu; D = 1024;
        const int lb = bid - 128;
        xcd = lb & 7; t = lb >> 3;                // t 0..3
    }
    const int cp = t & 1;
    const int rp = (t >> 1) * 8 + xcd;            // v: 0..63, u: 0..15
    const int r0 = rp * 64;
    const int c0 = cp * 128;
    const int wm  = (wave >> 1) * 32;             // 0,32
    const int wn2 = (wave & 1) * 64;              // 0,64

    // staging: thread -> (row srow, 8-short slot sq), source-slot XOR
    const int srow = tid >> 2, sq = tid & 3;
    const int qg = sq ^ ((srow >> 1) & 3);
    const short* xg  = X + (size_t)(r0 + srow) * D + qg * 8;
    const short* wg0 = W + (size_t)(c0 + srow) * D + qg * 8;
    const short* wg1 = W + (size_t)(c0 + 64 + srow) * D + qg * 8; // (64+srow)>>1&3 == (srow>>1)&3
    const int sxo = tid * 8;                      // shorts: srow*32 + sq*8

#define PSTG(bi, kc)                                                            \
    { GL2LDS(xg  + (kc), &Xs[bi][sxo]);                                         \
      GL2LDS(wg0 + (kc), &Wsh[bi][sxo]);                                        \
      GL2LDS(wg1 + (kc), &Wsh[bi][2048 + sxo]); }

    floatx4 acc[2][4] = {};
    const int aslot = (quad ^ ((l15 >> 1) & 3)) * 8;   // shorts within row

    PSTG(0, 0);
    __syncthreads();

    int cur = 0;
    for (int kc = 0; kc < D; kc += 32) {
        if (kc + 32 < D) { PSTG(cur ^ 1, kc + 32); }   // in flight across compute

        const short* xb = &Xs[cur][0];
        const short* wb = &Wsh[cur][0];
        short8 a[2], bfr[4];
#pragma unroll
        for (int tm = 0; tm < 2; tm++)
            a[tm] = *(const short8*)&xb[(wm + tm * 16 + l15) * 32 + aslot];
#pragma unroll
        for (int tn = 0; tn < 4; tn++)
            bfr[tn] = *(const short8*)&wb[(wn2 + tn * 16 + l15) * 32 + aslot];
#pragma unroll
        for (int tm = 0; tm < 2; tm++)
#pragma unroll
            for (int tn = 0; tn < 4; tn++)
                acc[tm][tn] = MFMA16(a[tm], bfr[tn], acc[tm][tn]);

        __syncthreads();   // drains GL2LDS (vmcnt0) -> next buf ready
        cur ^= 1;
    }
#undef PSTG

    // C/D layout: row = quad*4+reg (A-rows), col = l15 (B-rows)
    if (is_u) {
#pragma unroll
        for (int tm = 0; tm < 2; tm++)
#pragma unroll
            for (int tn = 0; tn < 4; tn++)
#pragma unroll
                for (int r = 0; r < 4; r++) {
                    const int row = r0 + wm + tm * 16 + quad * 4 + r;
                    const int col = c0 + wn2 + tn * 16 + l15;
                    upf[(size_t)row * 256 + col] = acc[tm][tn][r];
                }
    } else {
#pragma unroll
        for (int tm = 0; tm < 2; tm++)
#pragma unroll
            for (int tn = 0; tn < 4; tn++)
#pragma unroll
                for (int r = 0; r < 4; r++) {
                    const int row = r0 + wm + tm * 16 + quad * 4 + r;
                    const int col = c0 + wn2 + tn * 16 + l15;
                    vpb[(size_t)row * 256 + col] = f2bf(acc[tm][tn][r]);
                }
    }
}

// ---------------------------------------------------------------------------
// bilinear (v6 verbatim, best measured): block = (b, n-half, m); n64 x f256;
// 32 KB A' LDS; lb(256,4). A' = vp (.) up built once; barrier-free K-loop.
// ---------------------------------------------------------------------------
__global__ __launch_bounds__(256, 4) void bilinear_kernel(
    const float* __restrict__ up, const short* __restrict__ vp,
    const short* __restrict__ Wp_bf, const float* __restrict__ bp,
    float* __restrict__ out)
{
    __shared__ __align__(16) short A_lds[64 * 256];   // 32 KB, swizzled
    __shared__ float up_s[256];

    const int tid  = threadIdx.x;
    const int lane = tid & 63;
    const int wave = tid >> 6;
    const int quad = lane >> 4;
    const int l15  = lane & 15;

    // XCD-aware decode: the 64 blocks of one b (2 nhalf x 32 m) share bid%8.
    const int bid = blockIdx.x;
    const int xcd = bid & 7;
    const int grp = bid >> 3;                 // 0..255
    const int s   = grp & 63;
    const int b   = (grp >> 6) * 8 + xcd;     // 0..31
    const int m   = s >> 1;
    const int nh  = s & 1;
    const int bm  = b * 32 + m;

    // stage up row; vp loads issued BEFORE the barrier (latency overlaps)
    up_s[tid] = up[(size_t)bm * 256 + tid];

    const int kw = wave * 64;                 // wave-uniform k-quarter
    const short* vsrc = vp + (size_t)(b * 128 + nh * 64 + lane) * 256 + kw;
    short8 vv[8];
#pragma unroll
    for (int i = 0; i < 8; i++) vv[i] = *(const short8*)(vsrc + i * 8);

    __syncthreads();                          // up_s ready

    // build A' = vp (.) up (rows = lane, cols = kw..kw+63), XOR-swizzled
    {
        char* Ab = (char*)A_lds;
        const int rsw   = (lane & 7) << 4;
        const int rbase = lane * 512 + kw * 2;
#pragma unroll
        for (int i = 0; i < 8; i++) {
            const float4 ua = *(const float4*)&up_s[kw + i * 8];      // broadcast
            const float4 ub = *(const float4*)&up_s[kw + i * 8 + 4];  // broadcast
            uintx4 o;
            o[0] = scale2_rne(vv[i][0], vv[i][1], ua.x, ua.y);
            o[1] = scale2_rne(vv[i][2], vv[i][3], ua.z, ua.w);
            o[2] = scale2_rne(vv[i][4], vv[i][5], ub.x, ub.y);
            o[3] = scale2_rne(vv[i][6], vv[i][7], ub.z, ub.w);
            *(uintx4*)(Ab + ((rbase + i * 16) ^ rsw)) = o;
        }
    }
    __syncthreads();                          // A' ready; NO MORE BARRIERS

    // barrier-free K-loop (operand-swapped: D-rows = f, D-cols = n)
    floatx4 acc[4][4] = {};
    const char* Ab = (const char*)A_lds;
    const int aswz = (l15 & 7) << 4;
    const int wf   = wave * 64;               // wave-uniform f-quarter
    const short* wq = Wp_bf + (size_t)(wf + l15) * 256 + quad * 8;

    short8 bcur[4], bnxt[4];
#pragma unroll
    for (int tt = 0; tt < 4; tt++)
        bcur[tt] = *(const short8*)(wq + tt * 4096);

#pragma unroll
    for (int kc = 0; kc < 256; kc += 32) {
        if (kc < 224) {   // prefetch next chunk's B-frags (L2-hot Wp)
#pragma unroll
            for (int tt = 0; tt < 4; tt++)
                bnxt[tt] = *(const short8*)(wq + tt * 4096 + kc + 32);
        }
        short8 a[4];
#pragma unroll
        for (int tt = 0; tt < 4; tt++) {
            const int row = tt * 16 + l15;    // n-rows 0..63
            a[tt] = *(const short8*)(Ab + ((row * 512 + kc * 2 + quad * 16) ^ aswz));
        }
        __builtin_amdgcn_s_setprio(1);
#pragma unroll
        for (int tn = 0; tn < 4; tn++)
#pragma unroll
            for (int tf = 0; tf < 4; tf++)
                acc[tn][tf] = MFMA16(bcur[tf], a[tn], acc[tn][tf]);
        __builtin_amdgcn_s_setprio(0);
        if (kc < 224) {
#pragma unroll
            for (int tt = 0; tt < 4; tt++) bcur[tt] = bnxt[tt];
        }
    }

    // epilogue: f = wf + tf*16 + quad*4 + r (consecutive in r); n = nh*64+tn*16+l15
    float4 bpv[4];
#pragma unroll
    for (int tf = 0; tf < 4; tf++)
        bpv[tf] = *(const float4*)&bp[wf + tf * 16 + quad * 4];

    const size_t out_base = (size_t)bm * 128 * 256 + (size_t)(nh * 64) * 256;
#pragma unroll
    for (int tn = 0; tn < 4; tn++) {
        const int n = tn * 16 + l15;
        float* orow = out + out_base + (size_t)n * 256 + wf + quad * 4;
#pragma unroll
        for (int tf = 0; tf < 4; tf++) {
            float4 vo;
            vo.x = fmaxf(acc[tn][tf][0] + bpv[tf].x, 0.0f);
            vo.y = fmaxf(acc[tn][tf][1] + bpv[tf].y, 0.0f);
            vo.z = fmaxf(acc[tn][tf][2] + bpv[tf].z, 0.0f);
            vo.w = fmaxf(acc[tn][tf][3] + bpv[tf].w, 0.0f);
            *(float4*)(orow + tf * 16) = vo;
        }
    }
}

extern "C" void kernel_launch(void* const* d_in, const int* in_sizes, int n_in,
                              void* d_out, int out_size, void* d_ws, size_t ws_size,
                              hipStream_t stream) {
    const float* u  = (const float*)d_in[0];   // (32,32,1024)
    const float* v  = (const float*)d_in[1];   // (32,128,2048)
    const float* Wu = (const float*)d_in[2];   // (256,1024)
    const float* Wv = (const float*)d_in[3];   // (256,2048)
    const float* Wp = (const float*)d_in[4];   // (256,256)
    const float* bp = (const float*)d_in[5];   // (256,)
    float* out = (float*)d_out;                // (32,32,128,256)

    short* bf    = (short*)d_ws;
    short* u_bf  = bf;                 // 1,048,576
    short* v_bf  = u_bf + N_U;         // 8,388,608
    short* Wu_bf = v_bf + N_V;         // 262,144
    short* Wv_bf = Wu_bf + N_WU;       // 524,288
    short* Wp_bf = Wv_bf + N_WV;       // 65,536
    float* up_f  = (float*)(Wp_bf + N_WP);     // 1024x256 fp32
    short* vp_bf = (short*)(up_f + 262144);    // 4096x256 bf16

    convert_kernel<<<dim3(2048), dim3(256), 0, stream>>>(u, v, Wu, Wv, Wp, bf);
    proj_kernel<<<dim3(160), dim3(256), 0, stream>>>(
        u_bf, Wu_bf, up_f, v_bf, Wv_bf, vp_bf);
    bilinear_kernel<<<dim3(2048), dim3(256), 0, stream>>>(
        up_f, vp_bf, Wp_bf, bp, out);
}